// Round 4
// baseline (455.023 us; speedup 1.0000x reference)
//
#include <hip/hip_runtime.h>
#include <hip/hip_bf16.h>

typedef float f32x4 __attribute__((ext_vector_type(4)));
typedef short s16x8 __attribute__((ext_vector_type(8)));

#define NB   256
#define NU   512
#define ND0  512
#define ND1  1024
#define WROW (ND0 * ND1)   // elements per u-row of w

__device__ __forceinline__ unsigned int f2bf_pk(float a, float b) {
  __hip_bfloat16 ha = __float2bfloat16(a);
  __hip_bfloat16 hb = __float2bfloat16(b);
  unsigned short ua, ub;
  __builtin_memcpy(&ua, &ha, 2);
  __builtin_memcpy(&ub, &hb, 2);
  return (unsigned int)ua | ((unsigned int)ub << 16);
}

// CK-style barrier: enforces LDS ordering but does NOT drain vmcnt.
__device__ __forceinline__ void block_sync_lds() {
  asm volatile("s_waitcnt lgkmcnt(0)" ::: "memory");
  __builtin_amdgcn_s_barrier();
}

// async global->LDS DMA, 16B per lane; dest = ldsbase + lane*16 (linear).
__device__ __forceinline__ void glds16(const void* g, void* l) {
  __builtin_amdgcn_global_load_lds(
      (const __attribute__((address_space(1))) void*)g,
      (__attribute__((address_space(3))) void*)l, 16, 0, 0);
}

// Seed out[b,u] = bias[u]; main kernel atomically accumulates on top.
__global__ __launch_bounds__(256) void init_out(const float* __restrict__ bias,
                                                float* __restrict__ out) {
  int idx = blockIdx.x * 256 + threadIdx.x;   // 512 blocks -> 131072 = 256*512
  out[idx] = bias[idx & (NU - 1)];
}

// out(256x512) = Z(256x524288) @ W^T, Z[b, i*1024+j] = x[b,i]*y[b,j].
//
// R4 restructure: W staging via global_load_lds (fp32, double-buffered in
// LDS) instead of VGPR prefetch. Rationale: R1/R2 proved the 512-thread
// structure is pressure-locked at the 128-VGPR cliff, so the register
// pipeline cannot be deepened; its W-in-flight duty was only ~35% of the
// iteration (stall at the wv=wvn vmcnt(0)), giving 3.5/6.3 TB/s. Here the
// in-flight state lives in the LDS-DMA queue: W(t+1) is issued at the top
// of iter t and waited with a COUNTED vmcnt(2) at iter t+1 -> a full
// iteration in flight, never drained (m201 discipline).
//
// Grid: 256 blocks = 4 u-tiles (BN=128) x 64 K-chunks (8 i0 x full j).
// Block: 1024 threads, 16 waves (4m x 4n); per-wave 4 m-frags x 2 n-frags.
// LDS: Alds 32KB (256x64 bf16, XOR-swizzled) + Wlds 64KB (2 x 128x64 fp32).
// 96KB -> 1 block/CU, 4 waves/SIMD. W frags read as fp32 from LDS and
// packed to bf16 in-register (no separate convert phase / no Wbf16 tile).
//
// Swizzle: global_load_lds writes linearly, so the 16B-chunk XOR swizzle
// (chunk ^= row&7) is pre-applied to the per-lane GLOBAL source address;
// frag reads apply the same XOR (both-sides involution, m173/m201).
__global__ __launch_bounds__(1024, 4) void bilinear_kern(
    const float* __restrict__ x, const float* __restrict__ y,
    const float* __restrict__ w, float* __restrict__ out) {
  __shared__ __align__(16) char Alds[32768];   // 256 rows x 128B (64 bf16)
  __shared__ __align__(16) char Wlds[65536];   // 2 x (128 rows x 256B fp32)

  const int t    = threadIdx.x;
  const int lane = t & 63;
  const int l15  = lane & 15;
  const int lk   = lane >> 4;          // 0..3
  const int wid  = t >> 6;             // 0..15
  const int wm   = wid >> 2;           // 0..3  (m-group: rows wm*64)
  const int wn   = wid & 3;            // 0..3  (n-group: cols wn*32)

  const int nt    = blockIdx.x & 3;    // u-tile
  const int ic    = blockIdx.x >> 2;   // K-chunk: i0 in [ic*8, ic*8+8)
  const int ucol0 = nt * 128 + wn * 32;

  f32x4 acc[4][2];
#pragma unroll
  for (int mf = 0; mf < 4; ++mf)
#pragma unroll
    for (int nf = 0; nf < 2; ++nf)
#pragma unroll
      for (int r = 0; r < 4; ++r) acc[mf][nf][r] = 0.0f;

  // --- A staging: thread covers rows ar+64p (p=0..3), floats l15*4..+4 ---
  const int ar   = t >> 4;                        // 0..63
  const int awr  = ar * 128 + ((l15 * 8) ^ ((ar & 7) << 4));  // (row&7) inv. under +64p
  const float* yb = y + (size_t)ar * ND1 + l15 * 4;

  // --- W DMA staging map (2 issues/thread/iter): issue q covers LDS bytes
  // [wid*2048 + q*1024 + lane*16): row = wid*8 + q*4 + lk, chunkpos = l15.
  // LDS chunkpos p of row r must hold global chunk p ^ (r&7)  (r&7 = q*4+lk).
  const float* wg0 = w + (size_t)(nt * 128 + wid * 8 + lk) * WROW
                       + ((l15 ^ lk) * 4);
  const float* wg1 = w + (size_t)(nt * 128 + wid * 8 + 4 + lk) * WROW
                       + ((l15 ^ (4 + lk)) * 4);
  char* wd = Wlds + wid * 2048;        // + (buf<<15), +1024 for q=1

  // frag-read swizzle: frag rows have row&7 == l15&7 in both tiles
  const int afswz = (l15 & 7) << 4;

  // ---- prologue: DMA W tile 0 into buffer 0 ----
  {
    const size_t o0 = (size_t)(ic * 8) * ND1;
    glds16(wg0 + o0, wd);
    glds16(wg1 + o0, wd + 1024);
  }

  float xv[4];

  for (int it = 0; it < 128; ++it) {
    const int j0 = (it & 15) * 64;
    const int ii = ic * 8 + (it >> 4);

    block_sync_lds();   // barrier1: prev frag-reads done (both LDS tiles free)

    // x column for this i0 (every 16 iters). Issued BEFORE the W DMA so the
    // DMA stays youngest in the vmcnt FIFO; x retires at its A-synth use.
    if ((it & 15) == 0) {
#pragma unroll
      for (int p = 0; p < 4; ++p)
        xv[p] = x[(size_t)(ar + 64 * p) * ND0 + ii];
    }

    // ---- issue W(t+1) DMA into the other buffer (full iteration in flight) ----
    if (it < 127) {
      const int tn  = it + 1;
      const size_t on = (size_t)(ic * 8 + (tn >> 4)) * ND1 + (size_t)((tn & 15) * 64);
      char* dst = wd + ((size_t)(tn & 1) << 15);
      glds16(wg0 + on, dst);
      glds16(wg1 + on, dst + 1024);
    }

    // ---- A-tile synth: SY[b,jj] = bf16(x[b,i0]*y[b,j0+jj]) ----
#pragma unroll
    for (int p = 0; p < 4; ++p) {
      f32x4 v = *(const f32x4*)(yb + (size_t)p * 64 * ND1 + j0);
      unsigned long long pk =
          (unsigned long long)f2bf_pk(xv[p] * v[0], xv[p] * v[1]) |
          ((unsigned long long)f2bf_pk(xv[p] * v[2], xv[p] * v[3]) << 32);
      *(unsigned long long*)(Alds + awr + p * 8192) = pk;
    }

    // ---- counted wait: W(t) landed (own 2 DMA issues from last iter are the
    // oldest outstanding); W(t+1)'s 2 issues stay in flight. Then barrier. ----
    if (it < 127)
      asm volatile("s_waitcnt vmcnt(2) lgkmcnt(0)" ::: "memory");
    else
      asm volatile("s_waitcnt vmcnt(0) lgkmcnt(0)" ::: "memory");
    __builtin_amdgcn_s_barrier();   // barrier2: W(t) + A(t) visible block-wide

    // ---- MFMA over BK=64 (two k-steps of 32); W frags read fp32 -> pack bf16 ----
    const char* Wcur = Wlds + ((size_t)(it & 1) << 15);
#pragma unroll
    for (int ks = 0; ks < 2; ++ks) {
      s16x8 bfr[2];
#pragma unroll
      for (int nf = 0; nf < 2; ++nf) {
        const int row = wn * 32 + nf * 16 + l15;
        const int r7  = row & 7;
        const int c0  = ks * 8 + lk * 2;        // first 16B chunk of the 8 floats
        const char* base = Wcur + row * 256;
        f32x4 wlo = *(const f32x4*)(base + ((c0 ^ r7) << 4));
        f32x4 whi = *(const f32x4*)(base + (((c0 + 1) ^ r7) << 4));
        unsigned int pk[4] = { f2bf_pk(wlo[0], wlo[1]), f2bf_pk(wlo[2], wlo[3]),
                               f2bf_pk(whi[0], whi[1]), f2bf_pk(whi[2], whi[3]) };
        __builtin_memcpy(&bfr[nf], pk, 16);
      }
#pragma unroll
      for (int mf = 0; mf < 4; ++mf) {
        const int row = wm * 64 + mf * 16 + l15;
        s16x8 af = *(const s16x8*)(Alds + row * 128 + ((ks * 64 + lk * 16) ^ afswz));
        acc[mf][0] = __builtin_amdgcn_mfma_f32_16x16x32_bf16(af, bfr[0], acc[mf][0], 0, 0, 0);
        acc[mf][1] = __builtin_amdgcn_mfma_f32_16x16x32_bf16(af, bfr[1], acc[mf][1], 0, 0, 0);
      }
    }
  }

  // ---- epilogue: atomic accumulate partial tile into out ----
  // C/D layout: col = lane&15, row = (lane>>4)*4 + reg
#pragma unroll
  for (int mf = 0; mf < 4; ++mf) {
    const int grow = wm * 64 + mf * 16 + lk * 4;
#pragma unroll
    for (int nf = 0; nf < 2; ++nf) {
      const int gcol = ucol0 + nf * 16 + l15;
#pragma unroll
      for (int r = 0; r < 4; ++r) {
        atomicAdd(out + (size_t)(grow + r) * NU + gcol, acc[mf][nf][r]);
      }
    }
  }
}

extern "C" void kernel_launch(void* const* d_in, const int* in_sizes, int n_in,
                              void* d_out, int out_size, void* d_ws, size_t ws_size,
                              hipStream_t stream) {
  const float* x    = (const float*)d_in[0];
  const float* y    = (const float*)d_in[1];
  const float* w    = (const float*)d_in[2];
  const float* bias = (const float*)d_in[3];
  float* out = (float*)d_out;

  init_out<<<512, 256, 0, stream>>>(bias, out);
  bilinear_kern<<<256, 1024, 0, stream>>>(x, y, w, out);
}

// Round 5
// 363.911 us; speedup vs baseline: 1.2504x; 1.2504x over previous
//
#include <hip/hip_runtime.h>
#include <hip/hip_bf16.h>

typedef float f32x4 __attribute__((ext_vector_type(4)));
typedef short s16x8 __attribute__((ext_vector_type(8)));

#define NB   256
#define NU   512
#define ND0  512
#define ND1  1024
#define WROW (ND0 * ND1)   // elements per u-row of w

__device__ __forceinline__ unsigned int f2bf_pk(float a, float b) {
  __hip_bfloat16 ha = __float2bfloat16(a);
  __hip_bfloat16 hb = __float2bfloat16(b);
  unsigned short ua, ub;
  __builtin_memcpy(&ua, &ha, 2);
  __builtin_memcpy(&ub, &hb, 2);
  return (unsigned int)ua | ((unsigned int)ub << 16);
}

// CK-style barrier: enforces LDS ordering but does NOT drain vmcnt.
__device__ __forceinline__ void block_sync_lds() {
  asm volatile("s_waitcnt lgkmcnt(0)" ::: "memory");
  __builtin_amdgcn_s_barrier();
}

// async global->LDS DMA, 16B per lane; dest = wave-uniform base + lane*16.
__device__ __forceinline__ void glds16(const void* g, void* l) {
  __builtin_amdgcn_global_load_lds(
      (const __attribute__((address_space(1))) void*)g,
      (__attribute__((address_space(3))) void*)l, 16, 0, 0);
}

// Seed out[b,u] = bias[u]; main kernel atomically accumulates on top.
__global__ __launch_bounds__(256) void init_out(const float* __restrict__ bias,
                                                float* __restrict__ out) {
  int idx = blockIdx.x * 256 + threadIdx.x;   // 512 blocks -> 131072 = 256*512
  out[idx] = bias[idx & (NU - 1)];
}

// out(256x512) = Z(256x524288) @ W^T, Z[b, i*1024+j] = x[b,i]*y[b,j].
//
// R5 = R4 with the vmcnt FIFO bug fixed. R4 issued the W(t+1) DMAs BEFORE
// the A-synth y-loads; consuming the youngest y-load then forced the
// compiler to emit vmcnt(0), draining the DMA queue every iteration and
// exposing full HBM latency at the pack (hence 455us). Fix: issue y (and
// the periodic x) loads FIRST, pin the order with sched_barrier(0), THEN
// issue the 2 DMAs. The y-use wait becomes a counted vmcnt(2) that leaves
// the DMAs in flight for the whole iteration; the main loop never drains
// vmcnt (T4 discipline, now actually in the emitted code).
//
// Grid: 256 blocks = 4 u-tiles (BN=128) x 64 K-chunks (8 i0 x full j).
// Block: 1024 threads, 16 waves (4m x 4n); per-wave 4 m-frags x 2 n-frags.
// LDS: Alds 32KB (256x64 bf16, XOR-swizzled) + Wlds 64KB (2 x 128x64 fp32).
// 96KB -> 1 block/CU. W frags read fp32 from LDS, packed to bf16 in-reg.
//
// Swizzle: global_load_lds writes linearly, so the 16B-chunk XOR swizzle
// (chunk ^= row&7) is pre-applied to the per-lane GLOBAL source address;
// frag reads apply the same XOR (both-sides involution, m173/m201).
__global__ __launch_bounds__(1024, 4) void bilinear_kern(
    const float* __restrict__ x, const float* __restrict__ y,
    const float* __restrict__ w, float* __restrict__ out) {
  __shared__ __align__(16) char Alds[32768];   // 256 rows x 128B (64 bf16)
  __shared__ __align__(16) char Wlds[65536];   // 2 x (128 rows x 256B fp32)

  const int t    = threadIdx.x;
  const int lane = t & 63;
  const int l15  = lane & 15;
  const int lk   = lane >> 4;          // 0..3
  const int wid  = t >> 6;             // 0..15
  const int wm   = wid >> 2;           // 0..3  (m-group: rows wm*64)
  const int wn   = wid & 3;            // 0..3  (n-group: cols wn*32)

  const int nt    = blockIdx.x & 3;    // u-tile
  const int ic    = blockIdx.x >> 2;   // K-chunk: i0 in [ic*8, ic*8+8)
  const int ucol0 = nt * 128 + wn * 32;

  f32x4 acc[4][2];
#pragma unroll
  for (int mf = 0; mf < 4; ++mf)
#pragma unroll
    for (int nf = 0; nf < 2; ++nf)
#pragma unroll
      for (int r = 0; r < 4; ++r) acc[mf][nf][r] = 0.0f;

  // --- A staging: thread covers rows ar+64p (p=0..3), floats l15*4..+4 ---
  const int ar   = t >> 4;                        // 0..63
  const int awr  = ar * 128 + ((l15 * 8) ^ ((ar & 7) << 4));  // (row&7) inv. under +64p
  const float* yb = y + (size_t)ar * ND1 + l15 * 4;

  // --- W DMA staging map (2 issues/thread/iter): issue q covers LDS bytes
  // [wid*2048 + q*1024 + lane*16): row = wid*8 + q*4 + lk, chunkpos = l15.
  // LDS chunkpos p of row r must hold global chunk p ^ (r&7)  (r&7 = q*4+lk).
  const float* wg0 = w + (size_t)(nt * 128 + wid * 8 + lk) * WROW
                       + ((l15 ^ lk) * 4);
  const float* wg1 = w + (size_t)(nt * 128 + wid * 8 + 4 + lk) * WROW
                       + ((l15 ^ (4 + lk)) * 4);
  char* wd = Wlds + wid * 2048;        // + (buf<<15), +1024 for q=1

  // frag-read swizzle: frag rows have row&7 == l15&7 in both tiles
  const int afswz = (l15 & 7) << 4;

  // ---- prologue: DMA W tile 0 into buffer 0 ----
  {
    const size_t o0 = (size_t)(ic * 8) * ND1;
    glds16(wg0 + o0, wd);
    glds16(wg1 + o0, wd + 1024);
  }

  float xv[4];

  for (int it = 0; it < 128; ++it) {
    const int j0 = (it & 15) * 64;
    const int ii = ic * 8 + (it >> 4);

    block_sync_lds();   // barrier1: prev frag-reads done (both LDS tiles free)

    // ---- (1) issue ALL register loads for this iter FIRST (x every 16, y
    // always) so their data-dependence waits are COUNTED vmcnt(2) that
    // leave the DMAs in flight ----
    if ((it & 15) == 0) {
#pragma unroll
      for (int p = 0; p < 4; ++p)
        xv[p] = x[(size_t)(ar + 64 * p) * ND0 + ii];
    }
    f32x4 v[4];
#pragma unroll
    for (int p = 0; p < 4; ++p)
      v[p] = *(const f32x4*)(yb + (size_t)p * 64 * ND1 + j0);

    // pin issue order: nothing crosses this point (keeps DMAs youngest)
    __builtin_amdgcn_sched_barrier(0);

    // ---- (2) issue W(t+1) DMA into the other buffer ----
    if (it < 127) {
      const int tn  = it + 1;
      const size_t on = (size_t)(ic * 8 + (tn >> 4)) * ND1 + (size_t)((tn & 15) * 64);
      char* dst = wd + ((size_t)(tn & 1) << 15);
      glds16(wg0 + on, dst);
      glds16(wg1 + on, dst + 1024);
    }

    // ---- (3) A-tile synth: SY[b,jj] = bf16(x[b,i0]*y[b,j0+jj]) ----
    // (y-use here waits vmcnt(2): DMAs stay outstanding)
#pragma unroll
    for (int p = 0; p < 4; ++p) {
      unsigned long long pk =
          (unsigned long long)f2bf_pk(xv[p] * v[p][0], xv[p] * v[p][1]) |
          ((unsigned long long)f2bf_pk(xv[p] * v[p][2], xv[p] * v[p][3]) << 32);
      *(unsigned long long*)(Alds + awr + p * 8192) = pk;
    }

    // ---- (4) counted wait: everything older than the 2 in-flight DMAs
    // (i.e. W(t)'s DMAs from last iter) has retired; W(t+1) stays in flight ----
    if (it < 127)
      asm volatile("s_waitcnt vmcnt(2) lgkmcnt(0)" ::: "memory");
    else
      asm volatile("s_waitcnt vmcnt(0) lgkmcnt(0)" ::: "memory");
    __builtin_amdgcn_s_barrier();   // barrier2: W(t) + A(t) visible block-wide

    // ---- (5) MFMA over BK=64 (two k-steps of 32); W frags fp32 -> bf16 ----
    const char* Wcur = Wlds + ((size_t)(it & 1) << 15);
#pragma unroll
    for (int ks = 0; ks < 2; ++ks) {
      s16x8 bfr[2];
#pragma unroll
      for (int nf = 0; nf < 2; ++nf) {
        const int row = wn * 32 + nf * 16 + l15;
        const int r7  = row & 7;
        const int c0  = ks * 8 + lk * 2;        // first 16B chunk of the 8 floats
        const char* base = Wcur + row * 256;
        f32x4 wlo = *(const f32x4*)(base + ((c0 ^ r7) << 4));
        f32x4 whi = *(const f32x4*)(base + (((c0 + 1) ^ r7) << 4));
        unsigned int pk[4] = { f2bf_pk(wlo[0], wlo[1]), f2bf_pk(wlo[2], wlo[3]),
                               f2bf_pk(whi[0], whi[1]), f2bf_pk(whi[2], whi[3]) };
        __builtin_memcpy(&bfr[nf], pk, 16);
      }
#pragma unroll
      for (int mf = 0; mf < 4; ++mf) {
        const int row = wm * 64 + mf * 16 + l15;
        s16x8 af = *(const s16x8*)(Alds + row * 128 + ((ks * 64 + lk * 16) ^ afswz));
        acc[mf][0] = __builtin_amdgcn_mfma_f32_16x16x32_bf16(af, bfr[0], acc[mf][0], 0, 0, 0);
        acc[mf][1] = __builtin_amdgcn_mfma_f32_16x16x32_bf16(af, bfr[1], acc[mf][1], 0, 0, 0);
      }
    }
  }

  // ---- epilogue: atomic accumulate partial tile into out ----
  // C/D layout: col = lane&15, row = (lane>>4)*4 + reg
#pragma unroll
  for (int mf = 0; mf < 4; ++mf) {
    const int grow = wm * 64 + mf * 16 + lk * 4;
#pragma unroll
    for (int nf = 0; nf < 2; ++nf) {
      const int gcol = ucol0 + nf * 16 + l15;
#pragma unroll
      for (int r = 0; r < 4; ++r) {
        atomicAdd(out + (size_t)(grow + r) * NU + gcol, acc[mf][nf][r]);
      }
    }
  }
}

extern "C" void kernel_launch(void* const* d_in, const int* in_sizes, int n_in,
                              void* d_out, int out_size, void* d_ws, size_t ws_size,
                              hipStream_t stream) {
  const float* x    = (const float*)d_in[0];
  const float* y    = (const float*)d_in[1];
  const float* w    = (const float*)d_in[2];
  const float* bias = (const float*)d_in[3];
  float* out = (float*)d_out;

  init_out<<<512, 256, 0, stream>>>(bias, out);
  bilinear_kern<<<256, 1024, 0, stream>>>(x, y, w, out);
}

// Round 6
// 332.047 us; speedup vs baseline: 1.3704x; 1.0960x over previous
//
#include <hip/hip_runtime.h>
#include <hip/hip_bf16.h>

typedef float f32x4 __attribute__((ext_vector_type(4)));
typedef short s16x8 __attribute__((ext_vector_type(8)));

#define NB   256
#define NU   512
#define ND0  512
#define ND1  1024
#define WROW (ND0 * ND1)   // elements per u-row of w

__device__ __forceinline__ unsigned int f2bf_pk(float a, float b) {
  __hip_bfloat16 ha = __float2bfloat16(a);
  __hip_bfloat16 hb = __float2bfloat16(b);
  unsigned short ua, ub;
  __builtin_memcpy(&ua, &ha, 2);
  __builtin_memcpy(&ub, &hb, 2);
  return (unsigned int)ua | ((unsigned int)ub << 16);
}

// CK-style barrier: enforces LDS ordering but does NOT drain vmcnt,
// so register-prefetch global loads stay in flight across it.
__device__ __forceinline__ void block_sync_lds() {
  asm volatile("s_waitcnt lgkmcnt(0)" ::: "memory");
  __builtin_amdgcn_s_barrier();
}

// Seed out[b,u] = bias[u]; main kernel atomically accumulates on top.
__global__ __launch_bounds__(256) void init_out(const float* __restrict__ bias,
                                                float* __restrict__ out) {
  int idx = blockIdx.x * 256 + threadIdx.x;   // 512 blocks -> 131072 = 256*512
  out[idx] = bias[idx & (NU - 1)];
}

// out(256x512) = Z(256x524288) @ W^T, Z[b, i*1024+j] = x[b,i]*y[b,j].
// Grid: 512 blocks = 4 u-tiles (BN=128) x 128 K-chunks (4 i0's x full j each).
// Block: 512 threads, 8 waves (2m x 4n); per-wave 8 m-frags x 2 n-frags.
//
// R6 = R3 (297us, proven) with the loop body REORDERED so the depth-1
// register prefetch gets depth-2 timing:
//   R3 order: barrier1 -> A-synth -> pack(wv) -> issue wvn -> barrier2
//             -> MFMA -> copy wv=wvn (vmcnt(0): in flight only ~MFMA span,
//             ~15% duty -> 3.5 TB/s on W).
//   R6 order: barrier1 -> ISSUE wvn (top!) -> pack(wv) -> A-synth
//             -> xv rollover -> barrier2 -> MFMA -> copy (vmcnt(0) now
//             waits on loads a FULL iteration old: ~free).
// y-loads issue AFTER wvn, so their consume emits a counted vmcnt that
// leaves wvn in flight (R5's FIFO lesson). Window-by-window register
// liveness matches R3 (wv dies at pack before v[4] goes live; peak ~104),
// so no new pressure. W loads stay nontemporal (R3's win: W is single-use
// and must not evict the L2-resident y working set).
__global__ __launch_bounds__(512, 4) void bilinear_kern(
    const float* __restrict__ x, const float* __restrict__ y,
    const float* __restrict__ w, float* __restrict__ out) {
  __shared__ char Alds[32768];   // 256 rows x 128B (64 bf16), XOR-swizzled
  __shared__ char Wlds[16384];   // 128 rows x 128B (64 bf16), XOR-swizzled

  const int t    = threadIdx.x;
  const int lane = t & 63;
  const int l15  = lane & 15;
  const int lk   = lane >> 4;          // 0..3
  const int wid  = t >> 6;             // 0..7
  const int wm   = wid >> 2;           // 0..1  (m-group: rows wm*128)
  const int wn   = wid & 3;            // 0..3  (n-group: cols wn*32)

  const int nt    = blockIdx.x & 3;    // u-tile
  const int ic    = blockIdx.x >> 2;   // K-chunk: i0 in [ic*4, ic*4+4)
  const int ucol0 = nt * 128 + wn * 32;

  f32x4 acc[8][2];
#pragma unroll
  for (int mf = 0; mf < 8; ++mf)
#pragma unroll
    for (int nf = 0; nf < 2; ++nf)
#pragma unroll
      for (int r = 0; r < 4; ++r) acc[mf][nf][r] = 0.0f;

  // --- A staging map: thread covers rows ar+32p (p=0..7), floats l15*4..+4 ---
  const int ar   = t >> 4;                        // 0..31
  const int aswz = (ar & 7) << 4;                 // (row&7) invariant under +32p
  const int awr  = ar * 128 + ((l15 * 8) ^ aswz); // +p*4096
  const float* yb = y + (size_t)ar * ND1 + l15 * 4;

  // --- W staging map: thread covers rows wrb+4q (q=0..3), floats l15*4..+4 ---
  const int wrb = wid * 16 + lk;                  // 0..127 (wid*16+lk<128)
  const float* wq = w + (size_t)(nt * 128 + wrb) * WROW + l15 * 4;

  // frag-read swizzle: frag rows are l15 mod 8 in both tiles
  const int afswz = (l15 & 7) << 4;

  // ---- prologue: prefetch tile 0's W and the first x column ----
  f32x4 wv[4], wvn[4];
  {
    const float* p0 = wq + (size_t)(ic * 4) * ND1;
#pragma unroll
    for (int q = 0; q < 4; ++q)
      wv[q] = __builtin_nontemporal_load((const f32x4*)(p0 + (size_t)q * 4 * WROW));
  }
  float xv[8];
#pragma unroll
  for (int p = 0; p < 8; ++p)
    xv[p] = x[(size_t)(ar + 32 * p) * ND0 + ic * 4];

  for (int it = 0; it < 64; ++it) {
    const int j0 = (it & 15) * 64;

    block_sync_lds();   // barrier1: previous tiles fully consumed

    // ---- (1) issue W(t+1) prefetch FIRST: in flight for the entire
    // iteration (pack+synth+barrier+MFMA), retired at the bottom copy ----
    if (it < 63) {
      const int tn = it + 1;
      const int ii = ic * 4 + (tn >> 4);
      const int jn = (tn & 15) * 64;
      const float* pn = wq + (size_t)ii * ND1 + jn;
#pragma unroll
      for (int q = 0; q < 4; ++q)
        wvn[q] = __builtin_nontemporal_load((const f32x4*)(pn + (size_t)q * 4 * WROW));
    }
    // pin: nothing (esp. y-loads) may hoist above the wvn issue, so every
    // later data-wait is a COUNTED vmcnt that leaves wvn in flight
    __builtin_amdgcn_sched_barrier(0);

    // ---- (2) W-tile pack: wv (register-resident since last copy) -> LDS;
    // wv dies here, before v[4] goes live (no pressure overlap) ----
#pragma unroll
    for (int q = 0; q < 4; ++q) {
      const int row  = wrb + 4 * q;
      const int byte = row * 128 + ((l15 * 8) ^ ((row & 7) << 4));
      unsigned long long pk =
          (unsigned long long)f2bf_pk(wv[q][0], wv[q][1]) |
          ((unsigned long long)f2bf_pk(wv[q][2], wv[q][3]) << 32);
      *(unsigned long long*)(Wlds + byte) = pk;
    }

    // ---- (3) A-tile synth: SY[b,jj] = bf16(x[b,i0]*y[b,j0+jj]) ----
    // (y issued after wvn -> consume waits vmcnt(4), wvn stays in flight)
#pragma unroll
    for (int g = 0; g < 2; ++g) {
      f32x4 v[4];
#pragma unroll
      for (int pp = 0; pp < 4; ++pp)
        v[pp] = *(const f32x4*)(yb + (size_t)(g * 4 + pp) * 32 * ND1 + j0);
#pragma unroll
      for (int pp = 0; pp < 4; ++pp) {
        const int p = g * 4 + pp;
        unsigned long long pk =
            (unsigned long long)f2bf_pk(xv[p] * v[pp][0], xv[p] * v[pp][1]) |
            ((unsigned long long)f2bf_pk(xv[p] * v[pp][2], xv[p] * v[pp][3]) << 32);
        *(unsigned long long*)(Alds + awr + p * 4096) = pk;
      }
    }

    // ---- (4) xv rollover for the NEXT iteration (after this iteration's
    // A-synth consumed the current values; x-loads are youngest vmem and
    // are consumed an entire iteration later) ----
    if (it < 63 && (it & 15) == 15) {
      const int ii = ic * 4 + ((it + 1) >> 4);
#pragma unroll
      for (int pp = 0; pp < 8; ++pp)
        xv[pp] = x[(size_t)(ar + 32 * pp) * ND0 + ii];
    }

    block_sync_lds();   // barrier2: tiles visible (lgkmcnt only, no vm drain)

    // ---- (5) MFMA over BK=64 (two k-steps of 32) ----
#pragma unroll
    for (int ks = 0; ks < 2; ++ks) {
      const int kcol = ks * 64;
      s16x8 bf[2];
#pragma unroll
      for (int nf = 0; nf < 2; ++nf) {
        const int row = wn * 32 + nf * 16 + l15;
        bf[nf] = *(const s16x8*)(Wlds + row * 128 + ((kcol + lk * 16) ^ afswz));
      }
#pragma unroll
      for (int mf = 0; mf < 8; ++mf) {
        const int row = wm * 128 + mf * 16 + l15;
        s16x8 af = *(const s16x8*)(Alds + row * 128 + ((kcol + lk * 16) ^ afswz));
        acc[mf][0] = __builtin_amdgcn_mfma_f32_16x16x32_bf16(af, bf[0], acc[mf][0], 0, 0, 0);
        acc[mf][1] = __builtin_amdgcn_mfma_f32_16x16x32_bf16(af, bf[1], acc[mf][1], 0, 0, 0);
      }
    }

    // ---- (6) rotate: wvn (in flight since the TOP of this iteration ->
    // its vmcnt(0) here is ~free) becomes wv for the next pack ----
    if (it < 63) {
#pragma unroll
      for (int q = 0; q < 4; ++q) wv[q] = wvn[q];
    }
  }

  // ---- epilogue: atomic accumulate partial tile into out ----
  // C/D layout: col = lane&15, row = (lane>>4)*4 + reg
#pragma unroll
  for (int mf = 0; mf < 8; ++mf) {
    const int grow = wm * 128 + mf * 16 + lk * 4;
#pragma unroll
    for (int nf = 0; nf < 2; ++nf) {
      const int gcol = ucol0 + nf * 16 + l15;
#pragma unroll
      for (int r = 0; r < 4; ++r) {
        atomicAdd(out + (size_t)(grow + r) * NU + gcol, acc[mf][nf][r]);
      }
    }
  }
}

extern "C" void kernel_launch(void* const* d_in, const int* in_sizes, int n_in,
                              void* d_out, int out_size, void* d_ws, size_t ws_size,
                              hipStream_t stream) {
  const float* x    = (const float*)d_in[0];
  const float* y    = (const float*)d_in[1];
  const float* w    = (const float*)d_in[2];
  const float* bias = (const float*)d_in[3];
  float* out = (float*)d_out;

  init_out<<<512, 256, 0, stream>>>(bias, out);
  bilinear_kern<<<512, 512, 0, stream>>>(x, y, w, out);
}

// Round 7
// 295.147 us; speedup vs baseline: 1.5417x; 1.1250x over previous
//
#include <hip/hip_runtime.h>
#include <hip/hip_bf16.h>

typedef float f32x4 __attribute__((ext_vector_type(4)));
typedef short s16x8 __attribute__((ext_vector_type(8)));

#define NB   256
#define NU   512
#define ND0  512
#define ND1  1024
#define WROW (ND0 * ND1)   // elements per u-row of w

__device__ __forceinline__ unsigned int f2bf_pk(float a, float b) {
  __hip_bfloat16 ha = __float2bfloat16(a);
  __hip_bfloat16 hb = __float2bfloat16(b);
  unsigned short ua, ub;
  __builtin_memcpy(&ua, &ha, 2);
  __builtin_memcpy(&ub, &hb, 2);
  return (unsigned int)ua | ((unsigned int)ub << 16);
}

// CK-style barrier: enforces LDS ordering but does NOT drain vmcnt,
// so register-prefetch global loads stay in flight across it.
__device__ __forceinline__ void block_sync_lds() {
  asm volatile("s_waitcnt lgkmcnt(0)" ::: "memory");
  __builtin_amdgcn_s_barrier();
}

// Seed out[b,u] = bias[u]; main kernel atomically accumulates on top.
__global__ __launch_bounds__(256) void init_out(const float* __restrict__ bias,
                                                float* __restrict__ out) {
  int idx = blockIdx.x * 256 + threadIdx.x;   // 512 blocks -> 131072 = 256*512
  out[idx] = bias[idx & (NU - 1)];
}

// out(256x512) = Z(256x524288) @ W^T, Z[b, i*1024+j] = x[b,i]*y[b,j].
// Grid: 512 blocks = 4 u-tiles (BN=128) x 128 K-chunks (4 i0's x full j each).
// Block: 512 threads, 8 waves (2m x 4n); per-wave 8 m-frags x 2 n-frags.
//
// R7 = R3's body VERBATIM (297.6us; R2/R5/R6 proved every reorder of this
// loop regresses — compiler schedule is a local optimum, do not touch)
// + ONE index-arithmetic-only change: per-block START-PHASE STAGGER of
// the (i,j) K-sweep. Without it, the 4 blocks sharing an ic (nt=0..3)
// read addresses differing by exactly nt*256MB with identical low bits
// (same DRAM channel/bank phase, near-lockstep), and same-nt ic-neighbors
// share the same j-phase. off=(nt<<4)|(ic&15) rotates each block's sweep:
// same-ic blocks land on different i-columns (MB-apart pages), ic-chains
// decorrelate in j. SALU-only; VGPR liveness and body order unchanged;
// coverage of the K-chunk is a bijective rotation (correctness-free:
// fp32 atomic accumulation is order-independent).
__global__ __launch_bounds__(512, 4) void bilinear_kern(
    const float* __restrict__ x, const float* __restrict__ y,
    const float* __restrict__ w, float* __restrict__ out) {
  __shared__ char Alds[32768];   // 256 rows x 128B (64 bf16), XOR-swizzled
  __shared__ char Wlds[16384];   // 128 rows x 128B (64 bf16), XOR-swizzled

  const int t    = threadIdx.x;
  const int lane = t & 63;
  const int l15  = lane & 15;
  const int lk   = lane >> 4;          // 0..3
  const int wid  = t >> 6;             // 0..7
  const int wm   = wid >> 2;           // 0..1  (m-group: rows wm*128)
  const int wn   = wid & 3;            // 0..3  (n-group: cols wn*32)

  const int nt    = blockIdx.x & 3;    // u-tile
  const int ic    = blockIdx.x >> 2;   // K-chunk: i0 in [ic*4, ic*4+4)
  const int off   = (nt << 4) | (ic & 15);   // start phase, 0..63
  const int ucol0 = nt * 128 + wn * 32;

  f32x4 acc[8][2];
#pragma unroll
  for (int mf = 0; mf < 8; ++mf)
#pragma unroll
    for (int nf = 0; nf < 2; ++nf)
#pragma unroll
      for (int r = 0; r < 4; ++r) acc[mf][nf][r] = 0.0f;

  // --- A staging map: thread covers rows ar+32p (p=0..7), floats l15*4..+4 ---
  const int ar   = t >> 4;                        // 0..31
  const int aswz = (ar & 7) << 4;                 // (row&7) invariant under +32p
  const int awr  = ar * 128 + ((l15 * 8) ^ aswz); // +p*4096
  const float* yb = y + (size_t)ar * ND1 + l15 * 4;

  // --- W staging map: thread covers rows wrb+4q (q=0..3), floats l15*4..+4 ---
  const int wrb = wid * 16 + lk;                  // 0..127 (wid*16+lk<128)
  const float* wq = w + (size_t)(nt * 128 + wrb) * WROW + l15 * 4;

  // frag-read swizzle: frag rows are l15 mod 8 in both tiles
  const int afswz = (l15 & 7) << 4;

  // ---- prologue: prefetch step-0's W and its x column (staggered phase) ----
  f32x4 wv[4], wvn[4];
  const int ii0 = ic * 4 + (off >> 4);
  {
    const float* p0 = wq + (size_t)ii0 * ND1 + (off & 15) * 64;
#pragma unroll
    for (int q = 0; q < 4; ++q)
      wv[q] = __builtin_nontemporal_load((const f32x4*)(p0 + (size_t)q * 4 * WROW));
  }
  float xv[8];
#pragma unroll
  for (int p = 0; p < 8; ++p)
    xv[p] = x[(size_t)(ar + 32 * p) * ND0 + ii0];

  for (int it = 0; it < 64; ++it) {
    const int s  = (it + off) & 63;    // staggered sweep position
    const int j0 = (s & 15) * 64;

    block_sync_lds();   // barrier1: previous tiles fully consumed

    // ---- A-tile synth: SY[b,jj] = bf16(x[b,i0]*y[b,j0+jj]) ----
#pragma unroll
    for (int g = 0; g < 2; ++g) {
      f32x4 v[4];
#pragma unroll
      for (int pp = 0; pp < 4; ++pp)
        v[pp] = *(const f32x4*)(yb + (size_t)(g * 4 + pp) * 32 * ND1 + j0);
#pragma unroll
      for (int pp = 0; pp < 4; ++pp) {
        const int p = g * 4 + pp;
        unsigned long long pk =
            (unsigned long long)f2bf_pk(xv[p] * v[pp][0], xv[p] * v[pp][1]) |
            ((unsigned long long)f2bf_pk(xv[p] * v[pp][2], xv[p] * v[pp][3]) << 32);
        *(unsigned long long*)(Alds + awr + p * 4096) = pk;
      }
    }

    // ---- W-tile pack: fp32 regs -> bf16 LDS (swizzled); waits on wv here ----
#pragma unroll
    for (int q = 0; q < 4; ++q) {
      const int row  = wrb + 4 * q;
      const int byte = row * 128 + ((l15 * 8) ^ ((row & 7) << 4));
      unsigned long long pk =
          (unsigned long long)f2bf_pk(wv[q][0], wv[q][1]) |
          ((unsigned long long)f2bf_pk(wv[q][2], wv[q][3]) << 32);
      *(unsigned long long*)(Wlds + byte) = pk;
    }

    // ---- prefetch next step (stays in flight across barrier2 + MFMA) ----
    if (it < 63) {
      const int sn = (s + 1) & 63;
      const int ii = ic * 4 + (sn >> 4);
      const int jn = (sn & 15) * 64;
      const float* pn = wq + (size_t)ii * ND1 + jn;
#pragma unroll
      for (int q = 0; q < 4; ++q)
        wvn[q] = __builtin_nontemporal_load((const f32x4*)(pn + (size_t)q * 4 * WROW));
      if ((s & 15) == 15) {
#pragma unroll
        for (int pp = 0; pp < 8; ++pp)
          xv[pp] = x[(size_t)(ar + 32 * pp) * ND0 + ii];
      }
    }

    block_sync_lds();   // barrier2: tiles visible

    // ---- MFMA over BK=64 (two k-steps of 32) ----
#pragma unroll
    for (int ks = 0; ks < 2; ++ks) {
      const int kcol = ks * 64;
      s16x8 bf[2];
#pragma unroll
      for (int nf = 0; nf < 2; ++nf) {
        const int row = wn * 32 + nf * 16 + l15;
        bf[nf] = *(const s16x8*)(Wlds + row * 128 + ((kcol + lk * 16) ^ afswz));
      }
#pragma unroll
      for (int mf = 0; mf < 8; ++mf) {
        const int row = wm * 128 + mf * 16 + l15;
        s16x8 af = *(const s16x8*)(Alds + row * 128 + ((kcol + lk * 16) ^ afswz));
        acc[mf][0] = __builtin_amdgcn_mfma_f32_16x16x32_bf16(af, bf[0], acc[mf][0], 0, 0, 0);
        acc[mf][1] = __builtin_amdgcn_mfma_f32_16x16x32_bf16(af, bf[1], acc[mf][1], 0, 0, 0);
      }
    }

#pragma unroll
    for (int q = 0; q < 4; ++q) wv[q] = wvn[q];
  }

  // ---- epilogue: atomic accumulate partial tile into out ----
  // C/D layout: col = lane&15, row = (lane>>4)*4 + reg
#pragma unroll
  for (int mf = 0; mf < 8; ++mf) {
    const int grow = wm * 128 + mf * 16 + lk * 4;
#pragma unroll
    for (int nf = 0; nf < 2; ++nf) {
      const int gcol = ucol0 + nf * 16 + l15;
#pragma unroll
      for (int r = 0; r < 4; ++r) {
        atomicAdd(out + (size_t)(grow + r) * NU + gcol, acc[mf][nf][r]);
      }
    }
  }
}

extern "C" void kernel_launch(void* const* d_in, const int* in_sizes, int n_in,
                              void* d_out, int out_size, void* d_ws, size_t ws_size,
                              hipStream_t stream) {
  const float* x    = (const float*)d_in[0];
  const float* y    = (const float*)d_in[1];
  const float* w    = (const float*)d_in[2];
  const float* bias = (const float*)d_in[3];
  float* out = (float*)d_out;

  init_out<<<512, 256, 0, stream>>>(bias, out);
  bilinear_kern<<<512, 512, 0, stream>>>(x, y, w, out);
}

// Round 8
// 291.788 us; speedup vs baseline: 1.5594x; 1.0115x over previous
//
#include <hip/hip_runtime.h>
#include <hip/hip_bf16.h>

typedef float f32x4 __attribute__((ext_vector_type(4)));
typedef short s16x8 __attribute__((ext_vector_type(8)));

#define NB   256
#define NU   512
#define ND0  512
#define ND1  1024
#define WROW (ND0 * ND1)   // elements per u-row of w

// ws layout: f32x4 ws4[bid][mf*2+nf][t]  (512 x 16 x 512 f32x4 = 64 MB)
#define WS_BYTES ((size_t)512 * 16 * 512 * 16)

__device__ __forceinline__ unsigned int f2bf_pk(float a, float b) {
  __hip_bfloat16 ha = __float2bfloat16(a);
  __hip_bfloat16 hb = __float2bfloat16(b);
  unsigned short ua, ub;
  __builtin_memcpy(&ua, &ha, 2);
  __builtin_memcpy(&ub, &hb, 2);
  return (unsigned int)ua | ((unsigned int)ub << 16);
}

// CK-style barrier: enforces LDS ordering but does NOT drain vmcnt,
// so register-prefetch global loads stay in flight across it.
__device__ __forceinline__ void block_sync_lds() {
  asm volatile("s_waitcnt lgkmcnt(0)" ::: "memory");
  __builtin_amdgcn_s_barrier();
}

// Seed out[b,u] = bias[u]; atomic-fallback path only.
__global__ __launch_bounds__(256) void init_out(const float* __restrict__ bias,
                                                float* __restrict__ out) {
  int idx = blockIdx.x * 256 + threadIdx.x;   // 512 blocks -> 131072 = 256*512
  out[idx] = bias[idx & (NU - 1)];
}

// Reduce kernel (ws path): out[b,u] = bias[u] + sum_ic ws-partial.
// One thread per (b>>2, u) cell-group; reads are f32x4, wave-coalesced.
__global__ __launch_bounds__(256) void reduce_ws(
    const float* __restrict__ bias, const f32x4* __restrict__ ws4,
    float* __restrict__ out) {
  const int g  = blockIdx.x * 256 + threadIdx.x;   // 128 blocks -> 32768
  const int u  = g & 511;
  const int bh = g >> 9;                           // b>>2, 0..63
  const int wm = bh >> 5, mf = (bh >> 2) & 7, lk = bh & 3;
  const int ntile = u >> 7, wn = (u >> 5) & 3, nf = (u >> 4) & 1, l15 = u & 15;
  const int t  = (wm * 4 + wn) * 64 + lk * 16 + l15;
  const size_t base = (size_t)(mf * 2 + nf) * 512 + t;   // + bid*16*512

  f32x4 s0 = {0, 0, 0, 0}, s1 = {0, 0, 0, 0};
#pragma unroll 8
  for (int ic = 0; ic < 128; ic += 2) {
    s0 += ws4[base + (size_t)((ic + 0) * 4 + ntile) * (16 * 512)];
    s1 += ws4[base + (size_t)((ic + 1) * 4 + ntile) * (16 * 512)];
  }
  f32x4 s = s0 + s1;
  const float bv = bias[u];
  const int b0 = bh * 4;
#pragma unroll
  for (int r = 0; r < 4; ++r)
    out[(size_t)(b0 + r) * NU + u] = s[r] + bv;
}

// out(256x512) = Z(256x524288) @ W^T, Z[b, i*1024+j] = x[b,i]*y[b,j].
// Grid: 512 blocks = 4 u-tiles (BN=128) x 128 K-chunks (4 i0's x full j each).
// Block: 512 threads, 8 waves (2m x 4n); per-wave 8 m-frags x 2 n-frags.
//
// R8: main loop is R7 VERBATIM (295.1us best; R2/R5/R6 proved any body
// reorder regresses — in-order vmem retirement + VGPR cliff). Change is
// EPILOGUE-ONLY: when ws_size >= 64MB, blocks stream partial tiles to the
// workspace with coalesced nontemporal f32x4 stores (16/thread) instead
// of 64 contended f32 atomicAdds, and reduce_ws sums 128 partials/cell
// (+bias) — also eliminating the serialized init_out launch. Fallback
// (small ws): exact R7 atomic path. ws/use_ws live in SGPRs consumed
// after the loop -> zero impact on loop register allocation.
__global__ __launch_bounds__(512, 4) void bilinear_kern(
    const float* __restrict__ x, const float* __restrict__ y,
    const float* __restrict__ w, float* __restrict__ out,
    float* __restrict__ ws, int use_ws) {
  __shared__ char Alds[32768];   // 256 rows x 128B (64 bf16), XOR-swizzled
  __shared__ char Wlds[16384];   // 128 rows x 128B (64 bf16), XOR-swizzled

  const int t    = threadIdx.x;
  const int lane = t & 63;
  const int l15  = lane & 15;
  const int lk   = lane >> 4;          // 0..3
  const int wid  = t >> 6;             // 0..7
  const int wm   = wid >> 2;           // 0..1  (m-group: rows wm*128)
  const int wn   = wid & 3;            // 0..3  (n-group: cols wn*32)

  const int nt    = blockIdx.x & 3;    // u-tile
  const int ic    = blockIdx.x >> 2;   // K-chunk: i0 in [ic*4, ic*4+4)
  const int off   = (nt << 4) | (ic & 15);   // start phase, 0..63 (R7 stagger)
  const int ucol0 = nt * 128 + wn * 32;

  f32x4 acc[8][2];
#pragma unroll
  for (int mf = 0; mf < 8; ++mf)
#pragma unroll
    for (int nf = 0; nf < 2; ++nf)
#pragma unroll
      for (int r = 0; r < 4; ++r) acc[mf][nf][r] = 0.0f;

  // --- A staging map: thread covers rows ar+32p (p=0..7), floats l15*4..+4 ---
  const int ar   = t >> 4;                        // 0..31
  const int aswz = (ar & 7) << 4;                 // (row&7) invariant under +32p
  const int awr  = ar * 128 + ((l15 * 8) ^ aswz); // +p*4096
  const float* yb = y + (size_t)ar * ND1 + l15 * 4;

  // --- W staging map: thread covers rows wrb+4q (q=0..3), floats l15*4..+4 ---
  const int wrb = wid * 16 + lk;                  // 0..127 (wid*16+lk<128)
  const float* wq = w + (size_t)(nt * 128 + wrb) * WROW + l15 * 4;

  // frag-read swizzle: frag rows are l15 mod 8 in both tiles
  const int afswz = (l15 & 7) << 4;

  // ---- prologue: prefetch step-0's W and its x column (staggered phase) ----
  f32x4 wv[4], wvn[4];
  const int ii0 = ic * 4 + (off >> 4);
  {
    const float* p0 = wq + (size_t)ii0 * ND1 + (off & 15) * 64;
#pragma unroll
    for (int q = 0; q < 4; ++q)
      wv[q] = __builtin_nontemporal_load((const f32x4*)(p0 + (size_t)q * 4 * WROW));
  }
  float xv[8];
#pragma unroll
  for (int p = 0; p < 8; ++p)
    xv[p] = x[(size_t)(ar + 32 * p) * ND0 + ii0];

  for (int it = 0; it < 64; ++it) {
    const int s  = (it + off) & 63;    // staggered sweep position
    const int j0 = (s & 15) * 64;

    block_sync_lds();   // barrier1: previous tiles fully consumed

    // ---- A-tile synth: SY[b,jj] = bf16(x[b,i0]*y[b,j0+jj]) ----
#pragma unroll
    for (int g = 0; g < 2; ++g) {
      f32x4 v[4];
#pragma unroll
      for (int pp = 0; pp < 4; ++pp)
        v[pp] = *(const f32x4*)(yb + (size_t)(g * 4 + pp) * 32 * ND1 + j0);
#pragma unroll
      for (int pp = 0; pp < 4; ++pp) {
        const int p = g * 4 + pp;
        unsigned long long pk =
            (unsigned long long)f2bf_pk(xv[p] * v[pp][0], xv[p] * v[pp][1]) |
            ((unsigned long long)f2bf_pk(xv[p] * v[pp][2], xv[p] * v[pp][3]) << 32);
        *(unsigned long long*)(Alds + awr + p * 4096) = pk;
      }
    }

    // ---- W-tile pack: fp32 regs -> bf16 LDS (swizzled); waits on wv here ----
#pragma unroll
    for (int q = 0; q < 4; ++q) {
      const int row  = wrb + 4 * q;
      const int byte = row * 128 + ((l15 * 8) ^ ((row & 7) << 4));
      unsigned long long pk =
          (unsigned long long)f2bf_pk(wv[q][0], wv[q][1]) |
          ((unsigned long long)f2bf_pk(wv[q][2], wv[q][3]) << 32);
      *(unsigned long long*)(Wlds + byte) = pk;
    }

    // ---- prefetch next step (stays in flight across barrier2 + MFMA) ----
    if (it < 63) {
      const int sn = (s + 1) & 63;
      const int ii = ic * 4 + (sn >> 4);
      const int jn = (sn & 15) * 64;
      const float* pn = wq + (size_t)ii * ND1 + jn;
#pragma unroll
      for (int q = 0; q < 4; ++q)
        wvn[q] = __builtin_nontemporal_load((const f32x4*)(pn + (size_t)q * 4 * WROW));
      if ((s & 15) == 15) {
#pragma unroll
        for (int pp = 0; pp < 8; ++pp)
          xv[pp] = x[(size_t)(ar + 32 * pp) * ND0 + ii];
      }
    }

    block_sync_lds();   // barrier2: tiles visible

    // ---- MFMA over BK=64 (two k-steps of 32) ----
#pragma unroll
    for (int ks = 0; ks < 2; ++ks) {
      const int kcol = ks * 64;
      s16x8 bf[2];
#pragma unroll
      for (int nf = 0; nf < 2; ++nf) {
        const int row = wn * 32 + nf * 16 + l15;
        bf[nf] = *(const s16x8*)(Wlds + row * 128 + ((kcol + lk * 16) ^ afswz));
      }
#pragma unroll
      for (int mf = 0; mf < 8; ++mf) {
        const int row = wm * 128 + mf * 16 + l15;
        s16x8 af = *(const s16x8*)(Alds + row * 128 + ((kcol + lk * 16) ^ afswz));
        acc[mf][0] = __builtin_amdgcn_mfma_f32_16x16x32_bf16(af, bf[0], acc[mf][0], 0, 0, 0);
        acc[mf][1] = __builtin_amdgcn_mfma_f32_16x16x32_bf16(af, bf[1], acc[mf][1], 0, 0, 0);
      }
    }

#pragma unroll
    for (int q = 0; q < 4; ++q) wv[q] = wvn[q];
  }

  // ---- epilogue ----
  if (use_ws) {
    // coalesced nontemporal partial-tile store: ws4[bid][mf*2+nf][t]
    f32x4* ws4 = (f32x4*)ws + (size_t)blockIdx.x * (16 * 512) + t;
#pragma unroll
    for (int mf = 0; mf < 8; ++mf)
#pragma unroll
      for (int nf = 0; nf < 2; ++nf)
        __builtin_nontemporal_store(acc[mf][nf], ws4 + (mf * 2 + nf) * 512);
  } else {
    // atomic accumulate partial tile into out (R7 fallback)
    // C/D layout: col = lane&15, row = (lane>>4)*4 + reg
#pragma unroll
    for (int mf = 0; mf < 8; ++mf) {
      const int grow = wm * 128 + mf * 16 + lk * 4;
#pragma unroll
      for (int nf = 0; nf < 2; ++nf) {
        const int gcol = ucol0 + nf * 16 + l15;
#pragma unroll
        for (int r = 0; r < 4; ++r) {
          atomicAdd(out + (size_t)(grow + r) * NU + gcol, acc[mf][nf][r]);
        }
      }
    }
  }
}

extern "C" void kernel_launch(void* const* d_in, const int* in_sizes, int n_in,
                              void* d_out, int out_size, void* d_ws, size_t ws_size,
                              hipStream_t stream) {
  const float* x    = (const float*)d_in[0];
  const float* y    = (const float*)d_in[1];
  const float* w    = (const float*)d_in[2];
  const float* bias = (const float*)d_in[3];
  float* out = (float*)d_out;

  const bool use_ws = (d_ws != nullptr) && (ws_size >= WS_BYTES);
  if (use_ws) {
    bilinear_kern<<<512, 512, 0, stream>>>(x, y, w, out, (float*)d_ws, 1);
    reduce_ws<<<128, 256, 0, stream>>>(bias, (const f32x4*)d_ws, out);
  } else {
    init_out<<<512, 256, 0, stream>>>(bias, out);
    bilinear_kern<<<512, 512, 0, stream>>>(x, y, w, out, nullptr, 0);
  }
}